// Round 1
// baseline (1474.970 us; speedup 1.0000x reference)
//
#include <hip/hip_runtime.h>
#include <math.h>

#define NB 2
#define NL 1024
#define ND 1024
#define NH 2048
#define NE 8
#define NTOK (NB*NL)   // 2048 tokens
// total assignments = NTOK * 2 = 4096 always (top-2 distinct)

struct TokMeta { int i0, i1; float w0, w1; };

// ---------------- Router: RMSNorm + logits + softmax + top2 ----------------
// one wave per token; 4 waves per block
__global__ void router_kernel(const float* __restrict__ x,
                              const float* __restrict__ rscale,
                              const float* __restrict__ rw,
                              const float* __restrict__ pes,
                              int* __restrict__ counts,
                              TokMeta* __restrict__ meta)
{
    const int wave = threadIdx.x >> 6;
    const int lane = threadIdx.x & 63;
    const int t = blockIdx.x * 4 + wave;
    const float* xt = x + (size_t)t * ND;

    float part[NE];
#pragma unroll
    for (int e = 0; e < NE; ++e) part[e] = 0.f;
    float ss = 0.f;

#pragma unroll
    for (int i = 0; i < 4; ++i) {
        int d = (lane + 64 * i) * 4;               // float4 index, coalesced
        float4 xv = *(const float4*)(xt + d);
        float4 sv = *(const float4*)(rscale + d);
        float xs[4] = {xv.x, xv.y, xv.z, xv.w};
        float sc[4] = {sv.x, sv.y, sv.z, sv.w};
        const float* rwp = rw + (size_t)d * NE;
#pragma unroll
        for (int c = 0; c < 4; ++c) {
            float v = xs[c];
            ss += v * v;
            float xr = v * sc[c];
            float4 r0 = *(const float4*)(rwp + c * NE);
            float4 r1 = *(const float4*)(rwp + c * NE + 4);
            part[0] += xr * r0.x; part[1] += xr * r0.y;
            part[2] += xr * r0.z; part[3] += xr * r0.w;
            part[4] += xr * r1.x; part[5] += xr * r1.y;
            part[6] += xr * r1.z; part[7] += xr * r1.w;
        }
    }
    // wave butterfly reduction (width 64)
#pragma unroll
    for (int off = 32; off > 0; off >>= 1) {
        ss += __shfl_xor(ss, off, 64);
#pragma unroll
        for (int e = 0; e < NE; ++e) part[e] += __shfl_xor(part[e], off, 64);
    }
    if (lane == 0) {
        // logits = (x * rscale . rw) * rsqrt(mean(x^2)+eps) * rsqrt(D)
        float rinv = rsqrtf(ss * (1.f / ND) + 1e-6f) * rsqrtf((float)ND);
        float lg[NE];
#pragma unroll
        for (int e = 0; e < NE; ++e) lg[e] = part[e] * rinv;
        // top-1: first occurrence of max (strict >, ascending scan) matches lax.top_k ties
        int i0 = 0; float b0 = lg[0];
#pragma unroll
        for (int e = 1; e < NE; ++e) if (lg[e] > b0) { b0 = lg[e]; i0 = e; }
        int i1 = -1; float b1 = -INFINITY;
#pragma unroll
        for (int e = 0; e < NE; ++e) if (e != i0 && lg[e] > b1) { b1 = lg[e]; i1 = e; }
        // renormalized top-2 softmax weights: w0 = p0/(p0+p1), w1 = p1/(p0+p1)
        float e1 = expf(b1 - b0);
        float denom = 1.f + e1;
        float w0 = pes[i0] / denom;
        float w1 = pes[i1] * e1 / denom;
        meta[t].i0 = i0; meta[t].i1 = i1; meta[t].w0 = w0; meta[t].w1 = w1;
        atomicAdd(&counts[i0], 1);
        atomicAdd(&counts[i1], 1);
    }
}

// ---------------- tiny exclusive scan over 8 expert counts ----------------
__global__ void scan_kernel(const int* __restrict__ counts,
                            int* __restrict__ cursor, int* __restrict__ base)
{
    if (threadIdx.x == 0) {
        int acc = 0;
        for (int e = 0; e < NE; ++e) { base[e] = acc; cursor[e] = acc; acc += counts[e]; }
    }
}

// ---------------- scatter tokens into compact per-expert lists ----------------
__global__ void scatter_kernel(const TokMeta* __restrict__ meta, int* __restrict__ cursor,
                               int* __restrict__ tok_slot, float* __restrict__ w_slot)
{
    int t = blockIdx.x * blockDim.x + threadIdx.x;
    if (t >= NTOK) return;
    TokMeta m = meta[t];
    int s0 = atomicAdd(&cursor[m.i0], 1);
    tok_slot[s0] = t; w_slot[s0] = m.w0;
    int s1 = atomicAdd(&cursor[m.i1], 1);
    tok_slot[s1] = t; w_slot[s1] = m.w1;
}

// ---------------- gate GEMM: act[slot,h] = gelu(x.Wg0) * (x.Wg1) ----------------
// 64 tokens x 64 h tile, K-chunks of 16, 4x4 micro-tile per thread (x2 gates)
__global__ __launch_bounds__(256) void gate_gemm(const float* __restrict__ x,
                                                 const float* __restrict__ gw,
                                                 const int* __restrict__ base,
                                                 const int* __restrict__ counts,
                                                 const int* __restrict__ tok_slot,
                                                 float* __restrict__ act)
{
    const int e = blockIdx.z;
    const int n = counts[e];
    const int b0 = base[e];
    const int row0 = blockIdx.y * 64;
    if (row0 >= n) return;
    const int h0 = blockIdx.x * 64;

    __shared__ float As[64][20];   // pad 20: float4-aligned rows, conflict-light
    __shared__ float Bs0[64][20];
    __shared__ float Bs1[64][20];
    __shared__ int toks[64];

    const int tid = threadIdx.x;
    if (tid < 64) {
        int r = row0 + tid;
        toks[tid] = (r < n) ? tok_slot[b0 + r] : -1;
    }
    __syncthreads();

    const int lr = tid >> 2;         // load row 0..63
    const int lc = tid & 3;          // float4 group 0..3
    const int ty = tid >> 4, tx = tid & 15;

    const float* Wg0 = gw + ((size_t)e * 2 + 0) * NH * ND;
    const float* Wg1 = Wg0 + (size_t)NH * ND;

    float acc0[4][4] = {};
    float acc1[4][4] = {};

    for (int k0 = 0; k0 < ND; k0 += 16) {
        int tok = toks[lr];
        float4 av = make_float4(0.f, 0.f, 0.f, 0.f);
        if (tok >= 0) av = *(const float4*)(x + (size_t)tok * ND + k0 + lc * 4);
        *(float4*)&As[lr][lc * 4] = av;
        *(float4*)&Bs0[lr][lc * 4] = *(const float4*)(Wg0 + (size_t)(h0 + lr) * ND + k0 + lc * 4);
        *(float4*)&Bs1[lr][lc * 4] = *(const float4*)(Wg1 + (size_t)(h0 + lr) * ND + k0 + lc * 4);
        __syncthreads();

#pragma unroll
        for (int kk = 0; kk < 16; kk += 4) {
            float4 a[4], p[4], q[4];
#pragma unroll
            for (int i = 0; i < 4; ++i) a[i] = *(const float4*)&As[ty * 4 + i][kk];
#pragma unroll
            for (int j = 0; j < 4; ++j) {
                p[j] = *(const float4*)&Bs0[tx * 4 + j][kk];
                q[j] = *(const float4*)&Bs1[tx * 4 + j][kk];
            }
#pragma unroll
            for (int i = 0; i < 4; ++i)
#pragma unroll
                for (int j = 0; j < 4; ++j) {
                    acc0[i][j] += a[i].x * p[j].x + a[i].y * p[j].y + a[i].z * p[j].z + a[i].w * p[j].w;
                    acc1[i][j] += a[i].x * q[j].x + a[i].y * q[j].y + a[i].z * q[j].z + a[i].w * q[j].w;
                }
        }
        __syncthreads();
    }

    // epilogue: approximate (tanh) gelu(gate0) * gate1
#pragma unroll
    for (int i = 0; i < 4; ++i) {
        int r = row0 + ty * 4 + i;
        if (r < n) {
            float* ap = act + (size_t)(b0 + r) * NH + h0 + tx * 4;
#pragma unroll
            for (int j = 0; j < 4; ++j) {
                float g0 = acc0[i][j], g1 = acc1[i][j];
                float u = 0.7978845608028654f * (g0 + 0.044715f * g0 * g0 * g0);
                ap[j] = 0.5f * g0 * (1.f + tanhf(u)) * g1;
            }
        }
    }
}

// ---------------- down GEMM: out[tok,d] += w * act[slot,:] . Wl[e,:,d] ----------------
__global__ __launch_bounds__(256) void out_gemm(const float* __restrict__ act,
                                                const float* __restrict__ lw,
                                                const int* __restrict__ base,
                                                const int* __restrict__ counts,
                                                const int* __restrict__ tok_slot,
                                                const float* __restrict__ w_slot,
                                                float* __restrict__ out)
{
    const int e = blockIdx.z;
    const int n = counts[e];
    const int b0 = base[e];
    const int row0 = blockIdx.y * 64;
    if (row0 >= n) return;
    const int d0 = blockIdx.x * 64;

    __shared__ float As[64][20];   // act rows x 16 h-chunk
    __shared__ float Bs[16][68];   // Wl h-chunk x 64 d

    const float* Wl = lw + (size_t)e * NH * ND;
    const int tid = threadIdx.x;
    const int lr = tid >> 2, lc = tid & 3;     // A loads: 64 rows x 4 float4
    const int br = tid >> 4, bc = tid & 15;    // B loads: 16 rows x 16 float4
    const int ty = tid >> 4, tx = tid & 15;

    float acc[4][4] = {};

    for (int k0 = 0; k0 < NH; k0 += 16) {
        int r = row0 + lr;
        float4 av = make_float4(0.f, 0.f, 0.f, 0.f);
        if (r < n) av = *(const float4*)(act + (size_t)(b0 + r) * NH + k0 + lc * 4);
        *(float4*)&As[lr][lc * 4] = av;
        *(float4*)&Bs[br][bc * 4] = *(const float4*)(Wl + (size_t)(k0 + br) * ND + d0 + bc * 4);
        __syncthreads();

#pragma unroll
        for (int kk = 0; kk < 16; kk += 4) {
            float av4[4][4];
#pragma unroll
            for (int i = 0; i < 4; ++i) {
                float4 t4 = *(const float4*)&As[ty * 4 + i][kk];
                av4[i][0] = t4.x; av4[i][1] = t4.y; av4[i][2] = t4.z; av4[i][3] = t4.w;
            }
#pragma unroll
            for (int c = 0; c < 4; ++c) {
                float4 b = *(const float4*)&Bs[kk + c][tx * 4];
                float bv[4] = {b.x, b.y, b.z, b.w};
#pragma unroll
                for (int i = 0; i < 4; ++i)
#pragma unroll
                    for (int j = 0; j < 4; ++j)
                        acc[i][j] += av4[i][c] * bv[j];
            }
        }
        __syncthreads();
    }

#pragma unroll
    for (int i = 0; i < 4; ++i) {
        int r = row0 + ty * 4 + i;
        if (r < n) {
            int tok = tok_slot[b0 + r];
            float w = w_slot[b0 + r];
            float* op = out + (size_t)tok * ND + d0 + tx * 4;
#pragma unroll
            for (int j = 0; j < 4; ++j)
                atomicAdd(&op[j], acc[i][j] * w);
        }
    }
}

extern "C" void kernel_launch(void* const* d_in, const int* in_sizes, int n_in,
                              void* d_out, int out_size, void* d_ws, size_t ws_size,
                              hipStream_t stream)
{
    const float* x      = (const float*)d_in[0];
    const float* rscale = (const float*)d_in[1];
    const float* rw     = (const float*)d_in[2];
    const float* gw     = (const float*)d_in[3];
    const float* lw     = (const float*)d_in[4];
    const float* pes    = (const float*)d_in[5];
    float* out = (float*)d_out;

    // workspace layout (bytes):
    //   0    counts[8]  (zeroed each call)
    //   32   cursor[8]
    //   64   base[8]
    //   128  TokMeta[2048]            = 32768
    //   32896..  (aligned to 33024? no: 128+32768 = 32896) tok_slot[4096] = 16384
    //   49280 w_slot[4096]            = 16384
    //   65664 act[4096*2048] floats   = 33554432
    char* ws = (char*)d_ws;
    int* counts = (int*)ws;
    int* cursor = counts + 8;
    int* base   = counts + 16;
    TokMeta* meta  = (TokMeta*)(ws + 128);
    int*   tok_slot = (int*)(ws + 128 + 32768);
    float* w_slot   = (float*)(ws + 128 + 32768 + 16384);
    float* act      = (float*)(ws + 128 + 32768 + 16384 + 16384);  // 65664, 16B aligned

    hipMemsetAsync(d_ws, 0, 128, stream);
    hipMemsetAsync(d_out, 0, (size_t)out_size * sizeof(float), stream);

    router_kernel<<<NTOK / 4, 256, 0, stream>>>(x, rscale, rw, pes, counts, meta);
    scan_kernel<<<1, 64, 0, stream>>>(counts, cursor, base);
    scatter_kernel<<<NTOK / 256, 256, 0, stream>>>(meta, cursor, tok_slot, w_slot);

    dim3 g2(NH / 64, NTOK / 64, NE);   // h-tiles x worst-case token-tiles x experts
    gate_gemm<<<g2, 256, 0, stream>>>(x, gw, base, counts, tok_slot, act);

    dim3 g3(ND / 64, NTOK / 64, NE);
    out_gemm<<<g3, 256, 0, stream>>>(act, lw, base, counts, tok_slot, w_slot, out);
}

// Round 2
// 556.973 us; speedup vs baseline: 2.6482x; 2.6482x over previous
//
#include <hip/hip_runtime.h>
#include <math.h>

#define NB 2
#define NL 1024
#define ND 1024
#define NH 2048
#define NE 8
#define NTOK (NB*NL)   // 2048 tokens, 4096 assignments (top-2 distinct)

typedef float f32x4 __attribute__((ext_vector_type(4)));
typedef short s16x8 __attribute__((ext_vector_type(8)));

struct TokMeta { int i0, i1; float w0, w1; };

// float -> bf16 bits, round-to-nearest-even
__device__ __forceinline__ unsigned short f2bf(float f) {
    union { float f; unsigned u; } v; v.f = f;
    unsigned r = v.u + 0x7FFFu + ((v.u >> 16) & 1u);
    return (unsigned short)(r >> 16);
}

// ---------------- Router: RMSNorm + logits + softmax + top2 ----------------
__global__ void router_kernel(const float* __restrict__ x,
                              const float* __restrict__ rscale,
                              const float* __restrict__ rw,
                              const float* __restrict__ pes,
                              int* __restrict__ counts,
                              TokMeta* __restrict__ meta)
{
    const int wave = threadIdx.x >> 6;
    const int lane = threadIdx.x & 63;
    const int t = blockIdx.x * 4 + wave;
    const float* xt = x + (size_t)t * ND;

    float part[NE];
#pragma unroll
    for (int e = 0; e < NE; ++e) part[e] = 0.f;
    float ss = 0.f;

#pragma unroll
    for (int i = 0; i < 4; ++i) {
        int d = (lane + 64 * i) * 4;
        float4 xv = *(const float4*)(xt + d);
        float4 sv = *(const float4*)(rscale + d);
        float xs[4] = {xv.x, xv.y, xv.z, xv.w};
        float sc[4] = {sv.x, sv.y, sv.z, sv.w};
        const float* rwp = rw + (size_t)d * NE;
#pragma unroll
        for (int c = 0; c < 4; ++c) {
            float v = xs[c];
            ss += v * v;
            float xr = v * sc[c];
            float4 r0 = *(const float4*)(rwp + c * NE);
            float4 r1 = *(const float4*)(rwp + c * NE + 4);
            part[0] += xr * r0.x; part[1] += xr * r0.y;
            part[2] += xr * r0.z; part[3] += xr * r0.w;
            part[4] += xr * r1.x; part[5] += xr * r1.y;
            part[6] += xr * r1.z; part[7] += xr * r1.w;
        }
    }
#pragma unroll
    for (int off = 32; off > 0; off >>= 1) {
        ss += __shfl_xor(ss, off, 64);
#pragma unroll
        for (int e = 0; e < NE; ++e) part[e] += __shfl_xor(part[e], off, 64);
    }
    if (lane == 0) {
        float rinv = rsqrtf(ss * (1.f / ND) + 1e-6f) * rsqrtf((float)ND);
        float lg[NE];
#pragma unroll
        for (int e = 0; e < NE; ++e) lg[e] = part[e] * rinv;
        int i0 = 0; float b0 = lg[0];
#pragma unroll
        for (int e = 1; e < NE; ++e) if (lg[e] > b0) { b0 = lg[e]; i0 = e; }
        int i1 = -1; float b1 = -INFINITY;
#pragma unroll
        for (int e = 0; e < NE; ++e) if (e != i0 && lg[e] > b1) { b1 = lg[e]; i1 = e; }
        float e1 = expf(b1 - b0);
        float denom = 1.f + e1;
        float w0 = pes[i0] / denom;
        float w1 = pes[i1] * e1 / denom;
        meta[t].i0 = i0; meta[t].i1 = i1; meta[t].w0 = w0; meta[t].w1 = w1;
        atomicAdd(&counts[i0], 1);
        atomicAdd(&counts[i1], 1);
    }
}

__global__ void scan_kernel(const int* __restrict__ counts,
                            int* __restrict__ cursor, int* __restrict__ base)
{
    if (threadIdx.x == 0) {
        int acc = 0;
        for (int e = 0; e < NE; ++e) { base[e] = acc; cursor[e] = acc; acc += counts[e]; }
    }
}

__global__ void scatter_kernel(const TokMeta* __restrict__ meta, int* __restrict__ cursor,
                               int* __restrict__ tok_slot, float* __restrict__ w_slot)
{
    int t = blockIdx.x * blockDim.x + threadIdx.x;
    if (t >= NTOK) return;
    TokMeta m = meta[t];
    int s0 = atomicAdd(&cursor[m.i0], 1);
    tok_slot[s0] = t; w_slot[s0] = m.w0;
    int s1 = atomicAdd(&cursor[m.i1], 1);
    tok_slot[s1] = t; w_slot[s1] = m.w1;
}

// ---------------- gate GEMM (MFMA bf16): act = gelu(x.Wg0^T) * (x.Wg1^T) ----------------
// tile: 128 tokens x 64 h x both gates; 4 waves 2x2; wave = 64x32x2g (16 MFMAs/k-step)
#define BM 128
#define BH 64
#define BK 32
__global__ __launch_bounds__(256, 2) void gate_gemm(
    const float* __restrict__ x, const float* __restrict__ gw,
    const int* __restrict__ base, const int* __restrict__ counts,
    const int* __restrict__ tok_slot, unsigned short* __restrict__ act)
{
    const int e = blockIdx.z;
    const int n = counts[e];
    const int row0 = blockIdx.y * BM;
    if (row0 >= n) return;
    const int b0 = base[e];
    const int h0 = blockIdx.x * BH;

    __shared__ unsigned short As[BM][BK];      // [token][k] bf16
    __shared__ unsigned short Bs[2][BH][BK];   // [gate][h][k] bf16
    __shared__ int toks[BM];

    const int tid = threadIdx.x;
    if (tid < BM) {
        int r = row0 + tid;
        toks[tid] = (r < n) ? tok_slot[b0 + r] : -1;
    }
    __syncthreads();

    const int lane = tid & 63;
    const int wid  = tid >> 6;
    const int wm = wid & 1;          // token half (64)
    const int wn = wid >> 1;         // h half (32)
    const int srow = tid >> 1;       // staging row 0..127
    const int kh   = tid & 1;        // 16-float half of BK

    const int tok = toks[srow];
    const float* xa = x + (size_t)(tok < 0 ? 0 : tok) * ND + kh * 16;
    const int g  = srow >> 6;
    const int hh = srow & 63;
    const float* ba = gw + (((size_t)e * 2 + g) * NH + (h0 + hh)) * ND + kh * 16;

    f32x4 acc[2][4][2];
#pragma unroll
    for (int gg = 0; gg < 2; ++gg)
#pragma unroll
        for (int i = 0; i < 4; ++i)
#pragma unroll
            for (int j = 0; j < 2; ++j)
                acc[gg][i][j] = (f32x4){0.f, 0.f, 0.f, 0.f};

    const int fr = lane & 15;        // fragment row-within-16
    const int q8 = (lane >> 4) << 3; // k offset of this quad

    for (int k0 = 0; k0 < ND; k0 += BK) {
        // stage A (gathered x rows), fp32 -> bf16
        {
            float tmp[16];
            if (tok >= 0) {
                *(float4*)&tmp[0]  = *(const float4*)(xa + k0);
                *(float4*)&tmp[4]  = *(const float4*)(xa + k0 + 4);
                *(float4*)&tmp[8]  = *(const float4*)(xa + k0 + 8);
                *(float4*)&tmp[12] = *(const float4*)(xa + k0 + 12);
            } else {
#pragma unroll
                for (int i = 0; i < 16; ++i) tmp[i] = 0.f;
            }
            s16x8 v0, v1;
#pragma unroll
            for (int i = 0; i < 8; ++i) { v0[i] = (short)f2bf(tmp[i]); v1[i] = (short)f2bf(tmp[8 + i]); }
            *(s16x8*)&As[srow][kh * 16]     = v0;
            *(s16x8*)&As[srow][kh * 16 + 8] = v1;
        }
        // stage B (gate weights)
        {
            float tmp[16];
            *(float4*)&tmp[0]  = *(const float4*)(ba + k0);
            *(float4*)&tmp[4]  = *(const float4*)(ba + k0 + 4);
            *(float4*)&tmp[8]  = *(const float4*)(ba + k0 + 8);
            *(float4*)&tmp[12] = *(const float4*)(ba + k0 + 12);
            s16x8 v0, v1;
#pragma unroll
            for (int i = 0; i < 8; ++i) { v0[i] = (short)f2bf(tmp[i]); v1[i] = (short)f2bf(tmp[8 + i]); }
            *(s16x8*)&Bs[g][hh][kh * 16]     = v0;
            *(s16x8*)&Bs[g][hh][kh * 16 + 8] = v1;
        }
        __syncthreads();

        s16x8 af[4], bfr[2][2];
#pragma unroll
        for (int i = 0; i < 4; ++i)
            af[i] = *(const s16x8*)&As[wm * 64 + i * 16 + fr][q8];
#pragma unroll
        for (int gg = 0; gg < 2; ++gg)
#pragma unroll
            for (int j = 0; j < 2; ++j)
                bfr[gg][j] = *(const s16x8*)&Bs[gg][wn * 32 + j * 16 + fr][q8];
#pragma unroll
        for (int gg = 0; gg < 2; ++gg)
#pragma unroll
            for (int i = 0; i < 4; ++i)
#pragma unroll
                for (int j = 0; j < 2; ++j)
                    acc[gg][i][j] = __builtin_amdgcn_mfma_f32_16x16x32_bf16(
                        af[i], bfr[gg][j], acc[gg][i][j], 0, 0, 0);
        __syncthreads();
    }

    // epilogue: tanh-gelu(g0) * g1 -> act bf16 (C layout: col=lane&15, row=(lane>>4)*4+r)
    const int rb = (lane >> 4) * 4;
#pragma unroll
    for (int i = 0; i < 4; ++i)
#pragma unroll
        for (int r = 0; r < 4; ++r) {
            int rr = row0 + wm * 64 + i * 16 + rb + r;
            if (rr < n) {
#pragma unroll
                for (int j = 0; j < 2; ++j) {
                    float g0v = acc[0][i][j][r];
                    float g1v = acc[1][i][j][r];
                    float u = 0.7978845608028654f * (g0v + 0.044715f * g0v * g0v * g0v);
                    float ex = __expf(2.f * u);
                    float th = 1.f - 2.f / (ex + 1.f);
                    float a = 0.5f * g0v * (1.f + th) * g1v;
                    act[(size_t)(b0 + rr) * NH + (h0 + wn * 32 + j * 16 + fr)] = f2bf(a);
                }
            }
        }
}

// ---------------- down GEMM (MFMA bf16): out[tok] += w * act . Wl ----------------
// tile: 128 slots x 128 d, K=2048; B transposed during staging (lw is [h][d])
#define DBM 128
#define DBN 128
#define DBK 32
__global__ __launch_bounds__(256, 2) void down_gemm(
    const unsigned short* __restrict__ act, const float* __restrict__ lw,
    const int* __restrict__ base, const int* __restrict__ counts,
    const int* __restrict__ tok_slot, const float* __restrict__ w_slot,
    float* __restrict__ out)
{
    const int e = blockIdx.z;
    const int n = counts[e];
    const int row0 = blockIdx.y * DBM;
    if (row0 >= n) return;
    const int b0 = base[e];
    const int d0 = blockIdx.x * DBN;

    __shared__ unsigned short As[DBM][DBK];   // [slot][k(h)]
    __shared__ unsigned short Bs[DBN][DBK];   // [d][k(h)] (transposed in staging)
    __shared__ int stok[DBM];
    __shared__ float sw[DBM];

    const int tid = threadIdx.x;
    if (tid < DBM) {
        int r = row0 + tid;
        stok[tid] = (r < n) ? tok_slot[b0 + r] : -1;
        sw[tid]   = (r < n) ? w_slot[b0 + r] : 0.f;
    }
    __syncthreads();

    const int lane = tid & 63;
    const int wid  = tid >> 6;
    const int wm = wid & 1;
    const int wn = wid >> 1;

    // A staging: srow 0..127, kh half
    const int srow = tid >> 1;
    const int kh   = tid & 1;
    const bool arow_ok = (row0 + srow) < n;
    const unsigned short* aa = act + (size_t)(b0 + row0 + srow) * NH + kh * 16;

    // B staging: pair of k rows, 8 d-cols each
    const int kp = (tid & 15) * 2;   // k row pair 0..30
    const int cc = tid >> 4;         // 0..15 -> d cols cc*8..cc*8+7
    const float* lwb = lw + (size_t)e * NH * ND + (size_t)d0 + cc * 8;

    f32x4 acc[4][4];
#pragma unroll
    for (int i = 0; i < 4; ++i)
#pragma unroll
        for (int j = 0; j < 4; ++j)
            acc[i][j] = (f32x4){0.f, 0.f, 0.f, 0.f};

    const int fr = lane & 15;
    const int q8 = (lane >> 4) << 3;

    for (int k0 = 0; k0 < NH; k0 += DBK) {
        // stage A: bf16 rows of act, direct 16B copies
        {
            s16x8 v0, v1;
            if (arow_ok) {
                v0 = *(const s16x8*)(aa + k0);
                v1 = *(const s16x8*)(aa + k0 + 8);
            } else {
                v0 = (s16x8)0; v1 = (s16x8)0;
            }
            *(s16x8*)&As[srow][kh * 16]     = v0;
            *(s16x8*)&As[srow][kh * 16 + 8] = v1;
        }
        // stage B: read 2 k-rows (d-contiguous fp32), transpose+pack to [d][k] bf16
        {
            const float* p0 = lwb + (size_t)(k0 + kp) * ND;
            const float* p1 = p0 + ND;
            float r0[8], r1[8];
            *(float4*)&r0[0] = *(const float4*)(p0);
            *(float4*)&r0[4] = *(const float4*)(p0 + 4);
            *(float4*)&r1[0] = *(const float4*)(p1);
            *(float4*)&r1[4] = *(const float4*)(p1 + 4);
#pragma unroll
            for (int v = 0; v < 8; ++v) {
                unsigned pk = (unsigned)f2bf(r0[v]) | ((unsigned)f2bf(r1[v]) << 16);
                *(unsigned*)&Bs[cc * 8 + v][kp] = pk;
            }
        }
        __syncthreads();

        s16x8 af[4], bfr[4];
#pragma unroll
        for (int i = 0; i < 4; ++i)
            af[i] = *(const s16x8*)&As[wm * 64 + i * 16 + fr][q8];
#pragma unroll
        for (int j = 0; j < 4; ++j)
            bfr[j] = *(const s16x8*)&Bs[wn * 64 + j * 16 + fr][q8];
#pragma unroll
        for (int i = 0; i < 4; ++i)
#pragma unroll
            for (int j = 0; j < 4; ++j)
                acc[i][j] = __builtin_amdgcn_mfma_f32_16x16x32_bf16(af[i], bfr[j], acc[i][j], 0, 0, 0);
        __syncthreads();
    }

    const int rb = (lane >> 4) * 4;
#pragma unroll
    for (int i = 0; i < 4; ++i)
#pragma unroll
        for (int r = 0; r < 4; ++r) {
            int ml = wm * 64 + i * 16 + rb + r;
            int rr = row0 + ml;
            if (rr < n) {
                int tok = stok[ml];
                float w = sw[ml];
#pragma unroll
                for (int j = 0; j < 4; ++j)
                    atomicAdd(&out[(size_t)tok * ND + d0 + wn * 64 + j * 16 + fr],
                              w * acc[i][j][r]);
            }
        }
}

extern "C" void kernel_launch(void* const* d_in, const int* in_sizes, int n_in,
                              void* d_out, int out_size, void* d_ws, size_t ws_size,
                              hipStream_t stream)
{
    const float* x      = (const float*)d_in[0];
    const float* rscale = (const float*)d_in[1];
    const float* rw     = (const float*)d_in[2];
    const float* gw     = (const float*)d_in[3];
    const float* lw     = (const float*)d_in[4];
    const float* pes    = (const float*)d_in[5];
    float* out = (float*)d_out;

    // workspace layout:
    //   0      counts[8] / 32 cursor[8] / 64 base[8]   (zeroed each call)
    //   128    TokMeta[2048]        32768 B
    //   33024  tok_slot[4096]       16384 B
    //   49408  w_slot[4096]         16384 B
    //   65792  act bf16 [4096][2048] = 16777216 B   (total ~16.8 MB)
    char* ws = (char*)d_ws;
    int* counts = (int*)ws;
    int* cursor = counts + 8;
    int* base   = counts + 16;
    TokMeta* meta        = (TokMeta*)(ws + 128);
    int*   tok_slot      = (int*)(ws + 33024);
    float* w_slot        = (float*)(ws + 49408);
    unsigned short* act  = (unsigned short*)(ws + 65792);

    hipMemsetAsync(d_ws, 0, 128, stream);
    hipMemsetAsync(d_out, 0, (size_t)out_size * sizeof(float), stream);

    router_kernel<<<NTOK / 4, 256, 0, stream>>>(x, rscale, rw, pes, counts, meta);
    scan_kernel<<<1, 64, 0, stream>>>(counts, cursor, base);
    scatter_kernel<<<NTOK / 256, 256, 0, stream>>>(meta, cursor, tok_slot, w_slot);

    dim3 g2(NH / BH, NTOK / BM, NE);   // 32 x 16 x 8, early-exit on empty tiles
    gate_gemm<<<g2, 256, 0, stream>>>(x, gw, base, counts, tok_slot, act);

    dim3 g3(ND / DBN, NTOK / DBM, NE); // 8 x 16 x 8
    down_gemm<<<g3, 256, 0, stream>>>(act, lw, base, counts, tok_slot, w_slot, out);
}

// Round 3
// 461.399 us; speedup vs baseline: 3.1967x; 1.2071x over previous
//
#include <hip/hip_runtime.h>
#include <math.h>

#define NB 2
#define NL 1024
#define ND 1024
#define NH 2048
#define NE 8
#define NTOK (NB*NL)      // 2048 tokens
#define NSLOT (NTOK*2)    // 4096 assignments (top-2 distinct)

typedef float f32x4 __attribute__((ext_vector_type(4)));
typedef short s16x8 __attribute__((ext_vector_type(8)));
typedef short s16x4 __attribute__((ext_vector_type(4)));

struct TokMeta { int i0, i1; float w0, w1; };

__device__ __forceinline__ unsigned short f2bf(float f) {
    union { float f; unsigned u; } v; v.f = f;
    unsigned r = v.u + 0x7FFFu + ((v.u >> 16) & 1u);
    return (unsigned short)(r >> 16);
}

// ---------------- Router: RMSNorm + logits + softmax + top2 ----------------
__global__ void router_kernel(const float* __restrict__ x,
                              const float* __restrict__ rscale,
                              const float* __restrict__ rw,
                              const float* __restrict__ pes,
                              int* __restrict__ counts,
                              TokMeta* __restrict__ meta)
{
    const int wave = threadIdx.x >> 6;
    const int lane = threadIdx.x & 63;
    const int t = blockIdx.x * 4 + wave;
    const float* xt = x + (size_t)t * ND;

    float part[NE];
#pragma unroll
    for (int e = 0; e < NE; ++e) part[e] = 0.f;
    float ss = 0.f;

#pragma unroll
    for (int i = 0; i < 4; ++i) {
        int d = (lane + 64 * i) * 4;
        float4 xv = *(const float4*)(xt + d);
        float4 sv = *(const float4*)(rscale + d);
        float xs[4] = {xv.x, xv.y, xv.z, xv.w};
        float sc[4] = {sv.x, sv.y, sv.z, sv.w};
        const float* rwp = rw + (size_t)d * NE;
#pragma unroll
        for (int c = 0; c < 4; ++c) {
            float v = xs[c];
            ss += v * v;
            float xr = v * sc[c];
            float4 r0 = *(const float4*)(rwp + c * NE);
            float4 r1 = *(const float4*)(rwp + c * NE + 4);
            part[0] += xr * r0.x; part[1] += xr * r0.y;
            part[2] += xr * r0.z; part[3] += xr * r0.w;
            part[4] += xr * r1.x; part[5] += xr * r1.y;
            part[6] += xr * r1.z; part[7] += xr * r1.w;
        }
    }
#pragma unroll
    for (int off = 32; off > 0; off >>= 1) {
        ss += __shfl_xor(ss, off, 64);
#pragma unroll
        for (int e = 0; e < NE; ++e) part[e] += __shfl_xor(part[e], off, 64);
    }
    if (lane == 0) {
        float rinv = rsqrtf(ss * (1.f / ND) + 1e-6f) * rsqrtf((float)ND);
        float lg[NE];
#pragma unroll
        for (int e = 0; e < NE; ++e) lg[e] = part[e] * rinv;
        int i0 = 0; float b0 = lg[0];
#pragma unroll
        for (int e = 1; e < NE; ++e) if (lg[e] > b0) { b0 = lg[e]; i0 = e; }
        int i1 = -1; float b1 = -INFINITY;
#pragma unroll
        for (int e = 0; e < NE; ++e) if (e != i0 && lg[e] > b1) { b1 = lg[e]; i1 = e; }
        float e1 = expf(b1 - b0);
        float denom = 1.f + e1;
        float w0 = pes[i0] / denom;
        float w1 = pes[i1] * e1 / denom;
        meta[t].i0 = i0; meta[t].i1 = i1; meta[t].w0 = w0; meta[t].w1 = w1;
        atomicAdd(&counts[i0], 1);
        atomicAdd(&counts[i1], 1);
    }
}

__global__ void scan_kernel(const int* __restrict__ counts,
                            int* __restrict__ cursor, int* __restrict__ base)
{
    if (threadIdx.x == 0) {
        int acc = 0;
        for (int e = 0; e < NE; ++e) { base[e] = acc; cursor[e] = acc; acc += counts[e]; }
    }
}

__global__ void scatter_kernel(const TokMeta* __restrict__ meta, int* __restrict__ cursor,
                               int* __restrict__ tok_slot, float* __restrict__ w_slot)
{
    int t = blockIdx.x * blockDim.x + threadIdx.x;
    if (t >= NTOK) return;
    TokMeta m = meta[t];
    int s0 = atomicAdd(&cursor[m.i0], 1);
    tok_slot[s0] = t; w_slot[s0] = m.w0;
    int s1 = atomicAdd(&cursor[m.i1], 1);
    tok_slot[s1] = t; w_slot[s1] = m.w1;
}

// ---------------- gather_x: xg[slot][:] = bf16(x[tok_slot[slot]][:]) ----------------
__global__ __launch_bounds__(256) void gather_x(const float* __restrict__ x,
                                                const int* __restrict__ tok_slot,
                                                unsigned short* __restrict__ xg)
{
    const int s = blockIdx.x;
    const int tok = tok_slot[s];
    const int c = threadIdx.x * 4;
    float4 v = *(const float4*)(x + (size_t)tok * ND + c);
    s16x4 o;
    o[0] = (short)f2bf(v.x); o[1] = (short)f2bf(v.y);
    o[2] = (short)f2bf(v.z); o[3] = (short)f2bf(v.w);
    *(s16x4*)(xg + (size_t)s * ND + c) = o;
}

// ---------------- transpose_lw: lw fp32 [E][H][D] -> lwT bf16 [E][D][H] ----------------
__global__ __launch_bounds__(256) void transpose_lw(const float* __restrict__ lw,
                                                    unsigned short* __restrict__ lwT)
{
    const int e = blockIdx.z;
    const int h0 = blockIdx.y * 64;
    const int d0 = blockIdx.x * 64;
    __shared__ unsigned short T[64][66];

    const int tid = threadIdx.x;
    {   // load 64h x 64d, convert, store [h][d] in LDS
        const int hr = tid >> 2;
        const int dc = (tid & 3) * 16;
        const float* p = lw + ((size_t)e * NH + h0 + hr) * ND + d0 + dc;
        float t[16];
        *(float4*)&t[0]  = *(const float4*)(p);
        *(float4*)&t[4]  = *(const float4*)(p + 4);
        *(float4*)&t[8]  = *(const float4*)(p + 8);
        *(float4*)&t[12] = *(const float4*)(p + 12);
#pragma unroll
        for (int i = 0; i < 8; ++i) {
            unsigned pk = (unsigned)f2bf(t[2 * i]) | ((unsigned)f2bf(t[2 * i + 1]) << 16);
            *(unsigned*)&T[hr][dc + 2 * i] = pk;
        }
    }
    __syncthreads();
    {   // read transposed, write [d][h] contiguous
        const int dr = tid >> 2;
        const int hc = (tid & 3) * 16;
        s16x8 o0, o1;
#pragma unroll
        for (int i = 0; i < 8; ++i) o0[i] = (short)T[hc + i][dr];
#pragma unroll
        for (int i = 0; i < 8; ++i) o1[i] = (short)T[hc + 8 + i][dr];
        unsigned short* q = lwT + ((size_t)e * ND + d0 + dr) * NH + h0 + hc;
        *(s16x8*)(q)     = o0;
        *(s16x8*)(q + 8) = o1;
    }
}

// ---------------- gate GEMM (bf16 MFMA): act = w * gelu(xg.Wg0^T) * (xg.Wg1^T) ----------------
#define BM 128
#define BH 64
#define BK 32
__global__ __launch_bounds__(256, 2) void gate_gemm(
    const unsigned short* __restrict__ xg, const float* __restrict__ gw,
    const int* __restrict__ base, const int* __restrict__ counts,
    const float* __restrict__ w_slot, unsigned short* __restrict__ act)
{
    const int e = blockIdx.z;
    const int n = counts[e];
    const int row0 = blockIdx.y * BM;
    if (row0 >= n) return;
    const int b0 = base[e];
    const int h0 = blockIdx.x * BH;

    __shared__ unsigned short As[BM][BK];
    __shared__ unsigned short Bs[2][BH][BK];
    __shared__ float swv[BM];

    const int tid = threadIdx.x;
    if (tid < BM) {
        int r = row0 + tid;
        swv[tid] = (r < n) ? w_slot[b0 + r] : 0.f;
    }

    const int lane = tid & 63;
    const int wid  = tid >> 6;
    const int wm = wid & 1;
    const int wn = wid >> 1;
    const int srow = tid >> 1;
    const int kh   = tid & 1;

    const bool arow_ok = (row0 + srow) < n;
    const unsigned short* xa = xg + (size_t)(b0 + row0 + srow) * ND + kh * 16;
    const int g  = srow >> 6;
    const int hh = srow & 63;
    const float* ba = gw + (((size_t)e * 2 + g) * NH + (h0 + hh)) * ND + kh * 16;

    f32x4 acc[2][4][2];
#pragma unroll
    for (int gg = 0; gg < 2; ++gg)
#pragma unroll
        for (int i = 0; i < 4; ++i)
#pragma unroll
            for (int j = 0; j < 2; ++j)
                acc[gg][i][j] = (f32x4){0.f, 0.f, 0.f, 0.f};

    const int fr = lane & 15;
    const int q8 = (lane >> 4) << 3;

    for (int k0 = 0; k0 < ND; k0 += BK) {
        // A: bf16 direct copies (16 elems/thread)
        s16x8 a0 = (s16x8)0, a1 = (s16x8)0;
        if (arow_ok) {
            a0 = *(const s16x8*)(xa + k0);
            a1 = *(const s16x8*)(xa + k0 + 8);
        }
        // B: fp32 -> bf16 (16 elems/thread)
        float t[16];
        *(float4*)&t[0]  = *(const float4*)(ba + k0);
        *(float4*)&t[4]  = *(const float4*)(ba + k0 + 4);
        *(float4*)&t[8]  = *(const float4*)(ba + k0 + 8);
        *(float4*)&t[12] = *(const float4*)(ba + k0 + 12);
        s16x8 b0v, b1v;
#pragma unroll
        for (int i = 0; i < 8; ++i) { b0v[i] = (short)f2bf(t[i]); b1v[i] = (short)f2bf(t[8 + i]); }

        *(s16x8*)&As[srow][kh * 16]      = a0;
        *(s16x8*)&As[srow][kh * 16 + 8]  = a1;
        *(s16x8*)&Bs[g][hh][kh * 16]     = b0v;
        *(s16x8*)&Bs[g][hh][kh * 16 + 8] = b1v;
        __syncthreads();

        s16x8 af[4], bfr[2][2];
#pragma unroll
        for (int i = 0; i < 4; ++i)
            af[i] = *(const s16x8*)&As[wm * 64 + i * 16 + fr][q8];
#pragma unroll
        for (int gg = 0; gg < 2; ++gg)
#pragma unroll
            for (int j = 0; j < 2; ++j)
                bfr[gg][j] = *(const s16x8*)&Bs[gg][wn * 32 + j * 16 + fr][q8];
#pragma unroll
        for (int gg = 0; gg < 2; ++gg)
#pragma unroll
            for (int i = 0; i < 4; ++i)
#pragma unroll
                for (int j = 0; j < 2; ++j)
                    acc[gg][i][j] = __builtin_amdgcn_mfma_f32_16x16x32_bf16(
                        af[i], bfr[gg][j], acc[gg][i][j], 0, 0, 0);
        __syncthreads();
    }

    const int rb = (lane >> 4) * 4;
#pragma unroll
    for (int i = 0; i < 4; ++i)
#pragma unroll
        for (int r = 0; r < 4; ++r) {
            int ml = wm * 64 + i * 16 + rb + r;
            int rr = row0 + ml;
            if (rr < n) {
                float w = swv[ml];
#pragma unroll
                for (int j = 0; j < 2; ++j) {
                    float g0v = acc[0][i][j][r];
                    float g1v = acc[1][i][j][r];
                    float u = 0.7978845608028654f * (g0v + 0.044715f * g0v * g0v * g0v);
                    float ex = __expf(2.f * u);
                    float th = 1.f - 2.f / (ex + 1.f);
                    float a = 0.5f * g0v * (1.f + th) * g1v * w;
                    act[(size_t)(b0 + rr) * NH + (h0 + wn * 32 + j * 16 + fr)] = f2bf(a);
                }
            }
        }
}

// ---------------- down GEMM (bf16 MFMA, split-K=2): out[tok] += act . lwT^T ----------------
#define DBM 128
#define DBN 128
#define DBK 32
#define KSPLIT 2
#define KC (NH / KSPLIT)
__global__ __launch_bounds__(256, 2) void down_gemm(
    const unsigned short* __restrict__ act, const unsigned short* __restrict__ lwT,
    const int* __restrict__ base, const int* __restrict__ counts,
    const int* __restrict__ tok_slot, float* __restrict__ out)
{
    const int e  = blockIdx.z >> 1;
    const int kc = blockIdx.z & 1;
    const int n = counts[e];
    const int row0 = blockIdx.y * DBM;
    if (row0 >= n) return;
    const int b0 = base[e];
    const int d0 = blockIdx.x * DBN;

    __shared__ unsigned short As[DBM][DBK];
    __shared__ unsigned short Bs[DBN][DBK];
    __shared__ int stok[DBM];

    const int tid = threadIdx.x;
    if (tid < DBM) {
        int r = row0 + tid;
        stok[tid] = (r < n) ? tok_slot[b0 + r] : 0;
    }

    const int lane = tid & 63;
    const int wid  = tid >> 6;
    const int wm = wid & 1;
    const int wn = wid >> 1;
    const int srow = tid >> 1;
    const int kh   = tid & 1;

    const bool arow_ok = (row0 + srow) < n;
    const unsigned short* aa = act + (size_t)(b0 + row0 + srow) * NH + kc * KC + kh * 16;
    const unsigned short* bb = lwT + ((size_t)e * ND + d0 + srow) * NH + kc * KC + kh * 16;

    f32x4 acc[4][4];
#pragma unroll
    for (int i = 0; i < 4; ++i)
#pragma unroll
        for (int j = 0; j < 4; ++j)
            acc[i][j] = (f32x4){0.f, 0.f, 0.f, 0.f};

    const int fr = lane & 15;
    const int q8 = (lane >> 4) << 3;

    for (int k0 = 0; k0 < KC; k0 += DBK) {
        s16x8 a0 = (s16x8)0, a1 = (s16x8)0;
        if (arow_ok) {
            a0 = *(const s16x8*)(aa + k0);
            a1 = *(const s16x8*)(aa + k0 + 8);
        }
        s16x8 bv0 = *(const s16x8*)(bb + k0);
        s16x8 bv1 = *(const s16x8*)(bb + k0 + 8);

        *(s16x8*)&As[srow][kh * 16]     = a0;
        *(s16x8*)&As[srow][kh * 16 + 8] = a1;
        *(s16x8*)&Bs[srow][kh * 16]     = bv0;
        *(s16x8*)&Bs[srow][kh * 16 + 8] = bv1;
        __syncthreads();

        s16x8 af[4], bfr[4];
#pragma unroll
        for (int i = 0; i < 4; ++i)
            af[i] = *(const s16x8*)&As[wm * 64 + i * 16 + fr][q8];
#pragma unroll
        for (int j = 0; j < 4; ++j)
            bfr[j] = *(const s16x8*)&Bs[wn * 64 + j * 16 + fr][q8];
#pragma unroll
        for (int i = 0; i < 4; ++i)
#pragma unroll
            for (int j = 0; j < 4; ++j)
                acc[i][j] = __builtin_amdgcn_mfma_f32_16x16x32_bf16(af[i], bfr[j], acc[i][j], 0, 0, 0);
        __syncthreads();
    }

    const int rb = (lane >> 4) * 4;
#pragma unroll
    for (int i = 0; i < 4; ++i)
#pragma unroll
        for (int r = 0; r < 4; ++r) {
            int ml = wm * 64 + i * 16 + rb + r;
            int rr = row0 + ml;
            if (rr < n) {
                int tok = stok[ml];
#pragma unroll
                for (int j = 0; j < 4; ++j)
                    atomicAdd(&out[(size_t)tok * ND + d0 + wn * 64 + j * 16 + fr],
                              acc[i][j][r]);
            }
        }
}

extern "C" void kernel_launch(void* const* d_in, const int* in_sizes, int n_in,
                              void* d_out, int out_size, void* d_ws, size_t ws_size,
                              hipStream_t stream)
{
    const float* x      = (const float*)d_in[0];
    const float* rscale = (const float*)d_in[1];
    const float* rw     = (const float*)d_in[2];
    const float* gw     = (const float*)d_in[3];
    const float* lw     = (const float*)d_in[4];
    const float* pes    = (const float*)d_in[5];
    float* out = (float*)d_out;

    // workspace layout (bytes):
    //   0        counts[8]/cursor[8]/base[8] (zeroed)
    //   128      TokMeta[2048]        32768
    //   33024    tok_slot[4096]       16384
    //   49408    w_slot[4096]         16384
    //   65792    xg  bf16 [4096][1024]   8388608
    //   8454400  act bf16 [4096][2048]  16777216
    //   25231616 lwT bf16 [8][1024][2048] 33554432   (total ~58.8 MB)
    char* ws = (char*)d_ws;
    int* counts = (int*)ws;
    int* cursor = counts + 8;
    int* base   = counts + 16;
    TokMeta* meta        = (TokMeta*)(ws + 128);
    int*   tok_slot      = (int*)(ws + 33024);
    float* w_slot        = (float*)(ws + 49408);
    unsigned short* xg   = (unsigned short*)(ws + 65792);
    unsigned short* act  = (unsigned short*)(ws + 8454400);
    unsigned short* lwT  = (unsigned short*)(ws + 25231616);

    hipMemsetAsync(d_ws, 0, 128, stream);
    hipMemsetAsync(d_out, 0, (size_t)out_size * sizeof(float), stream);

    router_kernel<<<NTOK / 4, 256, 0, stream>>>(x, rscale, rw, pes, counts, meta);
    scan_kernel<<<1, 64, 0, stream>>>(counts, cursor, base);
    scatter_kernel<<<NTOK / 256, 256, 0, stream>>>(meta, cursor, tok_slot, w_slot);
    gather_x<<<NSLOT, 256, 0, stream>>>(x, tok_slot, xg);

    dim3 gt(ND / 64, NH / 64, NE);     // 16 x 32 x 8
    transpose_lw<<<gt, 256, 0, stream>>>(lw, lwT);

    dim3 g2(NH / BH, NTOK / BM, NE);   // 32 x 16 x 8
    gate_gemm<<<g2, 256, 0, stream>>>(xg, gw, base, counts, w_slot, act);

    dim3 g3(ND / DBN, NTOK / DBM, NE * KSPLIT); // 8 x 16 x 16
    down_gemm<<<g3, 256, 0, stream>>>(act, lwT, base, counts, tok_slot, out);
}

// Round 4
// 455.698 us; speedup vs baseline: 3.2367x; 1.0125x over previous
//
#include <hip/hip_runtime.h>
#include <math.h>

#define NB 2
#define NL 1024
#define ND 1024
#define NH 2048
#define NE 8
#define NTOK (NB*NL)      // 2048 tokens
#define NSLOT (NTOK*2)    // 4096 assignments (top-2 distinct)

typedef float f32x4 __attribute__((ext_vector_type(4)));
typedef short s16x8 __attribute__((ext_vector_type(8)));
typedef short s16x4 __attribute__((ext_vector_type(4)));

struct TokMeta { int i0, i1; float w0, w1; };

__device__ __forceinline__ unsigned short f2bf(float f) {
    union { float f; unsigned u; } v; v.f = f;
    unsigned r = v.u + 0x7FFFu + ((v.u >> 16) & 1u);
    return (unsigned short)(r >> 16);
}

// async global->LDS DMA, 16B per lane; LDS dest = uniform base + lane*16
__device__ __forceinline__ void gl_lds16(const unsigned short* g, unsigned short* l) {
    __builtin_amdgcn_global_load_lds(
        (const __attribute__((address_space(1))) unsigned int*)(const void*)g,
        (__attribute__((address_space(3))) unsigned int*)(void*)l, 16, 0, 0);
}

// ---------------- Router: RMSNorm + logits + softmax + top2 ----------------
__global__ void router_kernel(const float* __restrict__ x,
                              const float* __restrict__ rscale,
                              const float* __restrict__ rw,
                              const float* __restrict__ pes,
                              int* __restrict__ counts,
                              TokMeta* __restrict__ meta)
{
    const int wave = threadIdx.x >> 6;
    const int lane = threadIdx.x & 63;
    const int t = blockIdx.x * 4 + wave;
    const float* xt = x + (size_t)t * ND;

    float part[NE];
#pragma unroll
    for (int e = 0; e < NE; ++e) part[e] = 0.f;
    float ss = 0.f;

#pragma unroll
    for (int i = 0; i < 4; ++i) {
        int d = (lane + 64 * i) * 4;
        float4 xv = *(const float4*)(xt + d);
        float4 sv = *(const float4*)(rscale + d);
        float xs[4] = {xv.x, xv.y, xv.z, xv.w};
        float sc[4] = {sv.x, sv.y, sv.z, sv.w};
        const float* rwp = rw + (size_t)d * NE;
#pragma unroll
        for (int c = 0; c < 4; ++c) {
            float v = xs[c];
            ss += v * v;
            float xr = v * sc[c];
            float4 r0 = *(const float4*)(rwp + c * NE);
            float4 r1 = *(const float4*)(rwp + c * NE + 4);
            part[0] += xr * r0.x; part[1] += xr * r0.y;
            part[2] += xr * r0.z; part[3] += xr * r0.w;
            part[4] += xr * r1.x; part[5] += xr * r1.y;
            part[6] += xr * r1.z; part[7] += xr * r1.w;
        }
    }
#pragma unroll
    for (int off = 32; off > 0; off >>= 1) {
        ss += __shfl_xor(ss, off, 64);
#pragma unroll
        for (int e = 0; e < NE; ++e) part[e] += __shfl_xor(part[e], off, 64);
    }
    if (lane == 0) {
        float rinv = rsqrtf(ss * (1.f / ND) + 1e-6f) * rsqrtf((float)ND);
        float lg[NE];
#pragma unroll
        for (int e = 0; e < NE; ++e) lg[e] = part[e] * rinv;
        int i0 = 0; float b0 = lg[0];
#pragma unroll
        for (int e = 1; e < NE; ++e) if (lg[e] > b0) { b0 = lg[e]; i0 = e; }
        int i1 = -1; float b1 = -INFINITY;
#pragma unroll
        for (int e = 0; e < NE; ++e) if (e != i0 && lg[e] > b1) { b1 = lg[e]; i1 = e; }
        float e1 = expf(b1 - b0);
        float denom = 1.f + e1;
        float w0 = pes[i0] / denom;
        float w1 = pes[i1] * e1 / denom;
        meta[t].i0 = i0; meta[t].i1 = i1; meta[t].w0 = w0; meta[t].w1 = w1;
        atomicAdd(&counts[i0], 1);
        atomicAdd(&counts[i1], 1);
    }
}

__global__ void scan_kernel(const int* __restrict__ counts,
                            int* __restrict__ cursor, int* __restrict__ base)
{
    if (threadIdx.x == 0) {
        int acc = 0;
        for (int e = 0; e < NE; ++e) { base[e] = acc; cursor[e] = acc; acc += counts[e]; }
    }
}

__global__ void scatter_kernel(const TokMeta* __restrict__ meta, int* __restrict__ cursor,
                               int* __restrict__ tok_slot, float* __restrict__ w_slot)
{
    int t = blockIdx.x * blockDim.x + threadIdx.x;
    if (t >= NTOK) return;
    TokMeta m = meta[t];
    int s0 = atomicAdd(&cursor[m.i0], 1);
    tok_slot[s0] = t; w_slot[s0] = m.w0;
    int s1 = atomicAdd(&cursor[m.i1], 1);
    tok_slot[s1] = t; w_slot[s1] = m.w1;
}

// ---------------- convert_x: x fp32 [T][D] -> xb bf16 ----------------
__global__ __launch_bounds__(256) void convert_x(const float* __restrict__ x,
                                                 unsigned short* __restrict__ xb)
{
    const size_t i = ((size_t)blockIdx.x * 256 + threadIdx.x) * 8;
    float t[8];
    *(float4*)&t[0] = *(const float4*)(x + i);
    *(float4*)&t[4] = *(const float4*)(x + i + 4);
    s16x8 o;
#pragma unroll
    for (int c = 0; c < 8; ++c) o[c] = (short)f2bf(t[c]);
    *(s16x8*)(xb + i) = o;
}

// ---------------- convert_gw: gw fp32 -> gwb bf16 (same layout) ----------------
__global__ __launch_bounds__(256) void convert_gw(const float* __restrict__ gw,
                                                  unsigned short* __restrict__ gwb)
{
    const size_t i = ((size_t)blockIdx.x * 256 + threadIdx.x) * 8;
    float t[8];
    *(float4*)&t[0] = *(const float4*)(gw + i);
    *(float4*)&t[4] = *(const float4*)(gw + i + 4);
    s16x8 o;
#pragma unroll
    for (int c = 0; c < 8; ++c) o[c] = (short)f2bf(t[c]);
    *(s16x8*)(gwb + i) = o;
}

// ---------------- transpose_lw: lw fp32 [E][H][D] -> lwT bf16 [E][D][H] ----------------
__global__ __launch_bounds__(256) void transpose_lw(const float* __restrict__ lw,
                                                    unsigned short* __restrict__ lwT)
{
    const int e = blockIdx.z;
    const int h0 = blockIdx.y * 64;
    const int d0 = blockIdx.x * 64;
    __shared__ unsigned short T[64][66];

    const int tid = threadIdx.x;
    {
        const int hr = tid >> 2;
        const int dc = (tid & 3) * 16;
        const float* p = lw + ((size_t)e * NH + h0 + hr) * ND + d0 + dc;
        float t[16];
        *(float4*)&t[0]  = *(const float4*)(p);
        *(float4*)&t[4]  = *(const float4*)(p + 4);
        *(float4*)&t[8]  = *(const float4*)(p + 8);
        *(float4*)&t[12] = *(const float4*)(p + 12);
#pragma unroll
        for (int i = 0; i < 8; ++i) {
            unsigned pk = (unsigned)f2bf(t[2 * i]) | ((unsigned)f2bf(t[2 * i + 1]) << 16);
            *(unsigned*)&T[hr][dc + 2 * i] = pk;
        }
    }
    __syncthreads();
    {
        const int dr = tid >> 2;
        const int hc = (tid & 3) * 16;
        s16x8 o0, o1;
#pragma unroll
        for (int i = 0; i < 8; ++i) o0[i] = (short)T[hc + i][dr];
#pragma unroll
        for (int i = 0; i < 8; ++i) o1[i] = (short)T[hc + 8 + i][dr];
        unsigned short* q = lwT + ((size_t)e * ND + d0 + dr) * NH + h0 + hc;
        *(s16x8*)(q)     = o0;
        *(s16x8*)(q + 8) = o1;
    }
}

// ---------------- gate GEMM (bf16 MFMA + global_load_lds): ----------------
// act = w * gelu(xb[tok].Wg0^T) * (xb[tok].Wg1^T); tile 128 slots x 64 h x 2 gates
#define BM 128
#define BH 64
#define BK 32
__global__ __launch_bounds__(256, 2) void gate_gemm(
    const unsigned short* __restrict__ xb, const unsigned short* __restrict__ gwb,
    const int* __restrict__ base, const int* __restrict__ counts,
    const int* __restrict__ tok_slot, const float* __restrict__ w_slot,
    unsigned short* __restrict__ act)
{
    const int e = blockIdx.z;
    const int n = counts[e];
    const int row0 = blockIdx.y * BM;
    if (row0 >= n) return;
    const int b0 = base[e];
    const int h0 = blockIdx.x * BH;

    __shared__ unsigned short As[BM][BK];   // swizzled granules
    __shared__ unsigned short Bs[BM][BK];   // rows = g*64 + hh
    __shared__ int toks[BM];
    __shared__ float swv[BM];

    const int tid = threadIdx.x;
    if (tid < BM) {
        int r = row0 + tid;
        toks[tid] = (r < n) ? tok_slot[b0 + r] : 0;
        swv[tid]  = (r < n) ? w_slot[b0 + r] : 0.f;
    }
    __syncthreads();

    const int lane = tid & 63;
    const int wid  = tid >> 6;
    const int wm = wid & 1;
    const int wn = wid >> 1;

    // DMA source addressing: lane -> (row = R0 + lane/4, granule c = ((lane&3)-((lane>>3)&3))&3)
    const int drow = lane >> 2;
    const int c8  = (((lane & 3) - ((lane >> 3) & 3)) & 3) * 8;
    const int ar0 = wid * 32 + drow;
    const unsigned short* asrc0 = xb + (size_t)toks[ar0] * ND + c8;
    const unsigned short* asrc1 = xb + (size_t)toks[ar0 + 16] * ND + c8;
    // B rows: g*64+hh over [0,128)
    const int br0 = wid * 32 + drow;
    const int br1 = br0 + 16;
    const unsigned short* bsrc0 = gwb + (((size_t)e * 2 + (br0 >> 6)) * NH + h0 + (br0 & 63)) * ND + c8;
    const unsigned short* bsrc1 = gwb + (((size_t)e * 2 + (br1 >> 6)) * NH + h0 + (br1 & 63)) * ND + c8;

    f32x4 acc[2][4][2];
#pragma unroll
    for (int gg = 0; gg < 2; ++gg)
#pragma unroll
        for (int i = 0; i < 4; ++i)
#pragma unroll
            for (int j = 0; j < 2; ++j)
                acc[gg][i][j] = (f32x4){0.f, 0.f, 0.f, 0.f};

    const int fr = lane & 15;
    const int pS = (((lane >> 4) + (fr >> 1)) & 3) * 8;  // swizzled granule offset

    for (int k0 = 0; k0 < ND; k0 += BK) {
        gl_lds16(asrc0 + k0, &As[wid * 32][0]);
        gl_lds16(asrc1 + k0, &As[wid * 32 + 16][0]);
        gl_lds16(bsrc0 + k0, &Bs[wid * 32][0]);
        gl_lds16(bsrc1 + k0, &Bs[wid * 32 + 16][0]);
        __syncthreads();

        s16x8 af[4], bfr[2][2];
#pragma unroll
        for (int i = 0; i < 4; ++i)
            af[i] = *(const s16x8*)&As[wm * 64 + i * 16 + fr][pS];
#pragma unroll
        for (int gg = 0; gg < 2; ++gg)
#pragma unroll
            for (int j = 0; j < 2; ++j)
                bfr[gg][j] = *(const s16x8*)&Bs[gg * 64 + wn * 32 + j * 16 + fr][pS];
#pragma unroll
        for (int gg = 0; gg < 2; ++gg)
#pragma unroll
            for (int i = 0; i < 4; ++i)
#pragma unroll
                for (int j = 0; j < 2; ++j)
                    acc[gg][i][j] = __builtin_amdgcn_mfma_f32_16x16x32_bf16(
                        af[i], bfr[gg][j], acc[gg][i][j], 0, 0, 0);
        __syncthreads();
    }

    const int rb = (lane >> 4) * 4;
#pragma unroll
    for (int i = 0; i < 4; ++i)
#pragma unroll
        for (int r = 0; r < 4; ++r) {
            int ml = wm * 64 + i * 16 + rb + r;
            int rr = row0 + ml;
            if (rr < n) {
                float w = swv[ml];
#pragma unroll
                for (int j = 0; j < 2; ++j) {
                    float g0v = acc[0][i][j][r];
                    float g1v = acc[1][i][j][r];
                    float u = 0.7978845608028654f * (g0v + 0.044715f * g0v * g0v * g0v);
                    float ex = __expf(2.f * u);
                    float th = 1.f - 2.f / (ex + 1.f);
                    float a = 0.5f * g0v * (1.f + th) * g1v * w;
                    act[(size_t)(b0 + rr) * NH + (h0 + wn * 32 + j * 16 + fr)] = f2bf(a);
                }
            }
        }
}

// ---------------- down GEMM (bf16 MFMA + global_load_lds, split-K=2) ----------------
#define DBM 128
#define DBN 128
#define DBK 32
#define KSPLIT 2
#define KC (NH / KSPLIT)
__global__ __launch_bounds__(256, 2) void down_gemm(
    const unsigned short* __restrict__ act, const unsigned short* __restrict__ lwT,
    const int* __restrict__ base, const int* __restrict__ counts,
    const int* __restrict__ tok_slot, float* __restrict__ out)
{
    const int e  = blockIdx.z >> 1;
    const int kc = blockIdx.z & 1;
    const int n = counts[e];
    const int row0 = blockIdx.y * DBM;
    if (row0 >= n) return;
    const int b0 = base[e];
    const int d0 = blockIdx.x * DBN;

    __shared__ unsigned short As[DBM][DBK];
    __shared__ unsigned short Bs[DBN][DBK];
    __shared__ int stok[DBM];

    const int tid = threadIdx.x;
    if (tid < DBM) {
        int r = row0 + tid;
        stok[tid] = (r < n) ? tok_slot[b0 + r] : 0;
    }
    __syncthreads();

    const int lane = tid & 63;
    const int wid  = tid >> 6;
    const int wm = wid & 1;
    const int wn = wid >> 1;

    const int drow = lane >> 2;
    const int c8  = (((lane & 3) - ((lane >> 3) & 3)) & 3) * 8;
    const int ar0 = wid * 32 + drow;
    const int rr0 = row0 + ar0, rr1 = rr0 + 16;
    const int sl0 = b0 + (rr0 < n ? rr0 : 0);
    const int sl1 = b0 + (rr1 < n ? rr1 : 0);
    const unsigned short* asrc0 = act + (size_t)sl0 * NH + kc * KC + c8;
    const unsigned short* asrc1 = act + (size_t)sl1 * NH + kc * KC + c8;
    const unsigned short* bsrc0 = lwT + ((size_t)e * ND + d0 + ar0) * NH + kc * KC + c8;
    const unsigned short* bsrc1 = bsrc0 + 16 * NH;

    f32x4 acc[4][4];
#pragma unroll
    for (int i = 0; i < 4; ++i)
#pragma unroll
        for (int j = 0; j < 4; ++j)
            acc[i][j] = (f32x4){0.f, 0.f, 0.f, 0.f};

    const int fr = lane & 15;
    const int pS = (((lane >> 4) + (fr >> 1)) & 3) * 8;

    for (int k0 = 0; k0 < KC; k0 += DBK) {
        gl_lds16(asrc0 + k0, &As[wid * 32][0]);
        gl_lds16(asrc1 + k0, &As[wid * 32 + 16][0]);
        gl_lds16(bsrc0 + k0, &Bs[wid * 32][0]);
        gl_lds16(bsrc1 + k0, &Bs[wid * 32 + 16][0]);
        __syncthreads();

        s16x8 af[4], bfr[4];
#pragma unroll
        for (int i = 0; i < 4; ++i)
            af[i] = *(const s16x8*)&As[wm * 64 + i * 16 + fr][pS];
#pragma unroll
        for (int j = 0; j < 4; ++j)
            bfr[j] = *(const s16x8*)&Bs[wn * 64 + j * 16 + fr][pS];
#pragma unroll
        for (int i = 0; i < 4; ++i)
#pragma unroll
            for (int j = 0; j < 4; ++j)
                acc[i][j] = __builtin_amdgcn_mfma_f32_16x16x32_bf16(af[i], bfr[j], acc[i][j], 0, 0, 0);
        __syncthreads();
    }

    const int rb = (lane >> 4) * 4;
#pragma unroll
    for (int i = 0; i < 4; ++i)
#pragma unroll
        for (int r = 0; r < 4; ++r) {
            int ml = wm * 64 + i * 16 + rb + r;
            int rr = row0 + ml;
            if (rr < n) {
                int tok = stok[ml];
#pragma unroll
                for (int j = 0; j < 4; ++j)
                    atomicAdd(&out[(size_t)tok * ND + d0 + wn * 64 + j * 16 + fr],
                              acc[i][j][r]);
            }
        }
}

extern "C" void kernel_launch(void* const* d_in, const int* in_sizes, int n_in,
                              void* d_out, int out_size, void* d_ws, size_t ws_size,
                              hipStream_t stream)
{
    const float* x      = (const float*)d_in[0];
    const float* rscale = (const float*)d_in[1];
    const float* rw     = (const float*)d_in[2];
    const float* gw     = (const float*)d_in[3];
    const float* lw     = (const float*)d_in[4];
    const float* pes    = (const float*)d_in[5];
    float* out = (float*)d_out;

    // workspace layout (bytes):
    //   0         counts/cursor/base (128)
    //   128       TokMeta[2048]          32768
    //   33024     tok_slot[4096]         16384
    //   49408     w_slot[4096]           16384
    //   65792     xb  bf16 [2048][1024]   4194304
    //   4260096   act bf16 [4096][2048]  16777216
    //   21037312  lwT bf16 [8][1024][2048] 33554432
    //   54591744  gwb bf16 [8][2][2048][1024] 67108864   (total ~116 MB)
    char* ws = (char*)d_ws;
    int* counts = (int*)ws;
    int* cursor = counts + 8;
    int* base   = counts + 16;
    TokMeta* meta        = (TokMeta*)(ws + 128);
    int*   tok_slot      = (int*)(ws + 33024);
    float* w_slot        = (float*)(ws + 49408);
    unsigned short* xb   = (unsigned short*)(ws + 65792);
    unsigned short* act  = (unsigned short*)(ws + 4260096);
    unsigned short* lwT  = (unsigned short*)(ws + 21037312);
    unsigned short* gwb  = (unsigned short*)(ws + 54591744);

    hipMemsetAsync(d_ws, 0, 128, stream);
    hipMemsetAsync(d_out, 0, (size_t)out_size * sizeof(float), stream);

    router_kernel<<<NTOK / 4, 256, 0, stream>>>(x, rscale, rw, pes, counts, meta);
    scan_kernel<<<1, 64, 0, stream>>>(counts, cursor, base);
    scatter_kernel<<<NTOK / 256, 256, 0, stream>>>(meta, cursor, tok_slot, w_slot);

    convert_x<<<(NTOK * ND) / (256 * 8), 256, 0, stream>>>(x, xb);
    convert_gw<<<(NE * 2 * NH * ND) / (256 * 8), 256, 0, stream>>>(gw, gwb);
    dim3 gt(ND / 64, NH / 64, NE);
    transpose_lw<<<gt, 256, 0, stream>>>(lw, lwT);

    dim3 g2(NH / BH, NTOK / BM, NE);   // 32 x 16 x 8, early-exit
    gate_gemm<<<g2, 256, 0, stream>>>(xb, gwb, base, counts, tok_slot, w_slot, act);

    dim3 g3(ND / DBN, NTOK / DBM, NE * KSPLIT); // 8 x 16 x 16
    down_gemm<<<g3, 256, 0, stream>>>(act, lwT, base, counts, tok_slot, out);
}

// Round 5
// 433.726 us; speedup vs baseline: 3.4007x; 1.0507x over previous
//
#include <hip/hip_runtime.h>
#include <math.h>

#define NB 2
#define NL 1024
#define ND 1024
#define NH 2048
#define NE 8
#define NTOK (NB*NL)      // 2048 tokens; per-expert slot capacity = NTOK
#define NSLOT (NTOK*2)

typedef float f32x4 __attribute__((ext_vector_type(4)));
typedef short s16x8 __attribute__((ext_vector_type(8)));
typedef short s16x4 __attribute__((ext_vector_type(4)));

__device__ __forceinline__ unsigned short f2bf(float f) {
    union { float f; unsigned u; } v; v.f = f;
    unsigned r = v.u + 0x7FFFu + ((v.u >> 16) & 1u);
    return (unsigned short)(r >> 16);
}

// async global->LDS DMA, 16B per lane; LDS dest = uniform base + lane*16
__device__ __forceinline__ void gl_lds16(const unsigned short* g, unsigned short* l) {
    __builtin_amdgcn_global_load_lds(
        (const __attribute__((address_space(1))) unsigned int*)(const void*)g,
        (__attribute__((address_space(3))) unsigned int*)(void*)l, 16, 0, 0);
}

// ---------------- Router: RMSNorm + logits + top2 + scatter + x->bf16 ----------------
// one wave per token; 4 waves per block
__global__ void router_kernel(const float* __restrict__ x,
                              const float* __restrict__ rscale,
                              const float* __restrict__ rw,
                              const float* __restrict__ pes,
                              int* __restrict__ cursor,
                              int* __restrict__ tok_slot,
                              float* __restrict__ w_slot,
                              unsigned short* __restrict__ xb)
{
    const int wave = threadIdx.x >> 6;
    const int lane = threadIdx.x & 63;
    const int t = blockIdx.x * 4 + wave;
    const float* xt = x + (size_t)t * ND;
    unsigned short* xbt = xb + (size_t)t * ND;

    float part[NE];
#pragma unroll
    for (int e = 0; e < NE; ++e) part[e] = 0.f;
    float ss = 0.f;

#pragma unroll
    for (int i = 0; i < 4; ++i) {
        int d = (lane + 64 * i) * 4;
        float4 xv = *(const float4*)(xt + d);
        float4 sv = *(const float4*)(rscale + d);
        // side-effect: write bf16 copy of x
        s16x4 o;
        o[0] = (short)f2bf(xv.x); o[1] = (short)f2bf(xv.y);
        o[2] = (short)f2bf(xv.z); o[3] = (short)f2bf(xv.w);
        *(s16x4*)(xbt + d) = o;
        float xs[4] = {xv.x, xv.y, xv.z, xv.w};
        float sc[4] = {sv.x, sv.y, sv.z, sv.w};
        const float* rwp = rw + (size_t)d * NE;
#pragma unroll
        for (int c = 0; c < 4; ++c) {
            float v = xs[c];
            ss += v * v;
            float xr = v * sc[c];
            float4 r0 = *(const float4*)(rwp + c * NE);
            float4 r1 = *(const float4*)(rwp + c * NE + 4);
            part[0] += xr * r0.x; part[1] += xr * r0.y;
            part[2] += xr * r0.z; part[3] += xr * r0.w;
            part[4] += xr * r1.x; part[5] += xr * r1.y;
            part[6] += xr * r1.z; part[7] += xr * r1.w;
        }
    }
#pragma unroll
    for (int off = 32; off > 0; off >>= 1) {
        ss += __shfl_xor(ss, off, 64);
#pragma unroll
        for (int e = 0; e < NE; ++e) part[e] += __shfl_xor(part[e], off, 64);
    }
    if (lane == 0) {
        float rinv = rsqrtf(ss * (1.f / ND) + 1e-6f) * rsqrtf((float)ND);
        float lg[NE];
#pragma unroll
        for (int e = 0; e < NE; ++e) lg[e] = part[e] * rinv;
        int i0 = 0; float b0 = lg[0];
#pragma unroll
        for (int e = 1; e < NE; ++e) if (lg[e] > b0) { b0 = lg[e]; i0 = e; }
        int i1 = -1; float b1 = -INFINITY;
#pragma unroll
        for (int e = 0; e < NE; ++e) if (e != i0 && lg[e] > b1) { b1 = lg[e]; i1 = e; }
        float e1 = expf(b1 - b0);
        float denom = 1.f + e1;
        float w0 = pes[i0] / denom;
        float w1 = pes[i1] * e1 / denom;
        int s0 = atomicAdd(&cursor[i0], 1);
        tok_slot[i0 * NTOK + s0] = t; w_slot[i0 * NTOK + s0] = w0;
        int s1 = atomicAdd(&cursor[i1], 1);
        tok_slot[i1 * NTOK + s1] = t; w_slot[i1 * NTOK + s1] = w1;
    }
}

// ---------------- prep_weights: gw fp32 -> gwb bf16; lw [E][H][D] -> lwT bf16 [E][D][H] ----
#define GW_BLOCKS ((NE*2*NH*ND) / 2048)      // 16384
#define TL_BLOCKS ((ND/64)*(NH/64)*NE)       // 4096
__global__ __launch_bounds__(256) void prep_weights(const float* __restrict__ gw,
                                                    unsigned short* __restrict__ gwb,
                                                    const float* __restrict__ lw,
                                                    unsigned short* __restrict__ lwT)
{
    const int bid = blockIdx.x;
    const int tid = threadIdx.x;
    if (bid < GW_BLOCKS) {
        const size_t i = ((size_t)bid * 256 + tid) * 8;
        float t[8];
        *(float4*)&t[0] = *(const float4*)(gw + i);
        *(float4*)&t[4] = *(const float4*)(gw + i + 4);
        s16x8 o;
#pragma unroll
        for (int c = 0; c < 8; ++c) o[c] = (short)f2bf(t[c]);
        *(s16x8*)(gwb + i) = o;
        return;
    }
    const int b2 = bid - GW_BLOCKS;
    const int d0 = (b2 & 15) * 64;
    const int h0 = ((b2 >> 4) & 31) * 64;
    const int e  = b2 >> 9;
    __shared__ unsigned short T[64][66];
    {
        const int hr = tid >> 2;
        const int dc = (tid & 3) * 16;
        const float* p = lw + ((size_t)e * NH + h0 + hr) * ND + d0 + dc;
        float t[16];
        *(float4*)&t[0]  = *(const float4*)(p);
        *(float4*)&t[4]  = *(const float4*)(p + 4);
        *(float4*)&t[8]  = *(const float4*)(p + 8);
        *(float4*)&t[12] = *(const float4*)(p + 12);
#pragma unroll
        for (int i = 0; i < 8; ++i) {
            unsigned pk = (unsigned)f2bf(t[2 * i]) | ((unsigned)f2bf(t[2 * i + 1]) << 16);
            *(unsigned*)&T[hr][dc + 2 * i] = pk;
        }
    }
    __syncthreads();
    {
        const int dr = tid >> 2;
        const int hc = (tid & 3) * 16;
        s16x8 o0, o1;
#pragma unroll
        for (int i = 0; i < 8; ++i) o0[i] = (short)T[hc + i][dr];
#pragma unroll
        for (int i = 0; i < 8; ++i) o1[i] = (short)T[hc + 8 + i][dr];
        unsigned short* q = lwT + ((size_t)e * ND + d0 + dr) * NH + h0 + hc;
        *(s16x8*)(q)     = o0;
        *(s16x8*)(q + 8) = o1;
    }
}

// ---------------- gate GEMM (bf16 MFMA + global_load_lds) ----------------
#define BM 128
#define BH 64
#define BK 32
__global__ __launch_bounds__(256, 3) void gate_gemm(
    const unsigned short* __restrict__ xb, const unsigned short* __restrict__ gwb,
    const int* __restrict__ cursor,
    const int* __restrict__ tok_slot, const float* __restrict__ w_slot,
    unsigned short* __restrict__ act)
{
    const int e = blockIdx.z;
    const int n = cursor[e];
    const int row0 = blockIdx.y * BM;
    if (row0 >= n) return;
    const int b0 = e * NTOK;
    const int h0 = blockIdx.x * BH;

    __shared__ unsigned short As[BM][BK];
    __shared__ unsigned short Bs[BM][BK];   // rows = g*64 + hh
    __shared__ int toks[BM];
    __shared__ float swv[BM];

    const int tid = threadIdx.x;
    if (tid < BM) {
        int r = row0 + tid;
        toks[tid] = (r < n) ? tok_slot[b0 + r] : 0;
        swv[tid]  = (r < n) ? w_slot[b0 + r] : 0.f;
    }
    __syncthreads();

    const int lane = tid & 63;
    const int wid  = tid >> 6;
    const int wm = wid & 1;
    const int wn = wid >> 1;

    const int drow = lane >> 2;
    const int c8  = (((lane & 3) - ((lane >> 3) & 3)) & 3) * 8;
    const int ar0 = wid * 32 + drow;
    const unsigned short* asrc0 = xb + (size_t)toks[ar0] * ND + c8;
    const unsigned short* asrc1 = xb + (size_t)toks[ar0 + 16] * ND + c8;
    const int br0 = wid * 32 + drow;
    const int br1 = br0 + 16;
    const unsigned short* bsrc0 = gwb + (((size_t)e * 2 + (br0 >> 6)) * NH + h0 + (br0 & 63)) * ND + c8;
    const unsigned short* bsrc1 = gwb + (((size_t)e * 2 + (br1 >> 6)) * NH + h0 + (br1 & 63)) * ND + c8;

    f32x4 acc[2][4][2];
#pragma unroll
    for (int gg = 0; gg < 2; ++gg)
#pragma unroll
        for (int i = 0; i < 4; ++i)
#pragma unroll
            for (int j = 0; j < 2; ++j)
                acc[gg][i][j] = (f32x4){0.f, 0.f, 0.f, 0.f};

    const int fr = lane & 15;
    const int pS = (((lane >> 4) + (fr >> 1)) & 3) * 8;

    for (int k0 = 0; k0 < ND; k0 += BK) {
        gl_lds16(asrc0 + k0, &As[wid * 32][0]);
        gl_lds16(asrc1 + k0, &As[wid * 32 + 16][0]);
        gl_lds16(bsrc0 + k0, &Bs[wid * 32][0]);
        gl_lds16(bsrc1 + k0, &Bs[wid * 32 + 16][0]);
        __syncthreads();

        s16x8 af[4], bfr[2][2];
#pragma unroll
        for (int i = 0; i < 4; ++i)
            af[i] = *(const s16x8*)&As[wm * 64 + i * 16 + fr][pS];
#pragma unroll
        for (int gg = 0; gg < 2; ++gg)
#pragma unroll
            for (int j = 0; j < 2; ++j)
                bfr[gg][j] = *(const s16x8*)&Bs[gg * 64 + wn * 32 + j * 16 + fr][pS];
#pragma unroll
        for (int gg = 0; gg < 2; ++gg)
#pragma unroll
            for (int i = 0; i < 4; ++i)
#pragma unroll
                for (int j = 0; j < 2; ++j)
                    acc[gg][i][j] = __builtin_amdgcn_mfma_f32_16x16x32_bf16(
                        af[i], bfr[gg][j], acc[gg][i][j], 0, 0, 0);
        __syncthreads();
    }

    const int rb = (lane >> 4) * 4;
#pragma unroll
    for (int i = 0; i < 4; ++i)
#pragma unroll
        for (int r = 0; r < 4; ++r) {
            int ml = wm * 64 + i * 16 + rb + r;
            int rr = row0 + ml;
            if (rr < n) {
                float w = swv[ml];
#pragma unroll
                for (int j = 0; j < 2; ++j) {
                    float g0v = acc[0][i][j][r];
                    float g1v = acc[1][i][j][r];
                    float u = 0.7978845608028654f * (g0v + 0.044715f * g0v * g0v * g0v);
                    float ex = __expf(2.f * u);
                    float th = 1.f - 2.f / (ex + 1.f);
                    float a = 0.5f * g0v * (1.f + th) * g1v * w;
                    act[(size_t)(b0 + rr) * NH + (h0 + wn * 32 + j * 16 + fr)] = f2bf(a);
                }
            }
        }
}

// ---------------- down GEMM (bf16 MFMA + global_load_lds, split-K=2) ----------------
#define DBM 128
#define DBN 128
#define DBK 32
#define KSPLIT 2
#define KC (NH / KSPLIT)
__global__ __launch_bounds__(256, 3) void down_gemm(
    const unsigned short* __restrict__ act, const unsigned short* __restrict__ lwT,
    const int* __restrict__ cursor,
    const int* __restrict__ tok_slot, float* __restrict__ out)
{
    const int e  = blockIdx.z >> 1;
    const int kc = blockIdx.z & 1;
    const int n = cursor[e];
    const int row0 = blockIdx.y * DBM;
    if (row0 >= n) return;
    const int b0 = e * NTOK;
    const int d0 = blockIdx.x * DBN;

    __shared__ unsigned short As[DBM][DBK];
    __shared__ unsigned short Bs[DBN][DBK];
    __shared__ int stok[DBM];

    const int tid = threadIdx.x;
    if (tid < DBM) {
        int r = row0 + tid;
        stok[tid] = (r < n) ? tok_slot[b0 + r] : 0;
    }
    __syncthreads();

    const int lane = tid & 63;
    const int wid  = tid >> 6;
    const int wm = wid & 1;
    const int wn = wid >> 1;

    const int drow = lane >> 2;
    const int c8  = (((lane & 3) - ((lane >> 3) & 3)) & 3) * 8;
    const int ar0 = wid * 32 + drow;
    const int rr0 = row0 + ar0, rr1 = rr0 + 16;
    const int sl0 = b0 + (rr0 < n ? rr0 : 0);
    const int sl1 = b0 + (rr1 < n ? rr1 : 0);
    const unsigned short* asrc0 = act + (size_t)sl0 * NH + kc * KC + c8;
    const unsigned short* asrc1 = act + (size_t)sl1 * NH + kc * KC + c8;
    const unsigned short* bsrc0 = lwT + ((size_t)e * ND + d0 + ar0) * NH + kc * KC + c8;
    const unsigned short* bsrc1 = bsrc0 + 16 * NH;

    f32x4 acc[4][4];
#pragma unroll
    for (int i = 0; i < 4; ++i)
#pragma unroll
        for (int j = 0; j < 4; ++j)
            acc[i][j] = (f32x4){0.f, 0.f, 0.f, 0.f};

    const int fr = lane & 15;
    const int pS = (((lane >> 4) + (fr >> 1)) & 3) * 8;

    for (int k0 = 0; k0 < KC; k0 += DBK) {
        gl_lds16(asrc0 + k0, &As[wid * 32][0]);
        gl_lds16(asrc1 + k0, &As[wid * 32 + 16][0]);
        gl_lds16(bsrc0 + k0, &Bs[wid * 32][0]);
        gl_lds16(bsrc1 + k0, &Bs[wid * 32 + 16][0]);
        __syncthreads();

        s16x8 af[4], bfr[4];
#pragma unroll
        for (int i = 0; i < 4; ++i)
            af[i] = *(const s16x8*)&As[wm * 64 + i * 16 + fr][pS];
#pragma unroll
        for (int j = 0; j < 4; ++j)
            bfr[j] = *(const s16x8*)&Bs[wn * 64 + j * 16 + fr][pS];
#pragma unroll
        for (int i = 0; i < 4; ++i)
#pragma unroll
            for (int j = 0; j < 4; ++j)
                acc[i][j] = __builtin_amdgcn_mfma_f32_16x16x32_bf16(af[i], bfr[j], acc[i][j], 0, 0, 0);
        __syncthreads();
    }

    const int rb = (lane >> 4) * 4;
#pragma unroll
    for (int i = 0; i < 4; ++i)
#pragma unroll
        for (int r = 0; r < 4; ++r) {
            int ml = wm * 64 + i * 16 + rb + r;
            int rr = row0 + ml;
            if (rr < n) {
                int tok = stok[ml];
#pragma unroll
                for (int j = 0; j < 4; ++j)
                    atomicAdd(&out[(size_t)tok * ND + d0 + wn * 64 + j * 16 + fr],
                              acc[i][j][r]);
            }
        }
}

extern "C" void kernel_launch(void* const* d_in, const int* in_sizes, int n_in,
                              void* d_out, int out_size, void* d_ws, size_t ws_size,
                              hipStream_t stream)
{
    const float* x      = (const float*)d_in[0];
    const float* rscale = (const float*)d_in[1];
    const float* rw     = (const float*)d_in[2];
    const float* gw     = (const float*)d_in[3];
    const float* lw     = (const float*)d_in[4];
    const float* pes    = (const float*)d_in[5];
    float* out = (float*)d_out;

    // workspace layout (bytes), ws >= 512MB per observed poison fill:
    //   0          cursor[8] (zeroed, doubles as counts)
    //   128        tok_slot[8][2048]        65536
    //   65664      w_slot[8][2048]          65536
    //   131200     xb  bf16 [2048][1024]     4194304
    //   4325504    act bf16 [8*2048][2048]  67108864
    //   71434368   lwT bf16 [8][1024][2048] 33554432
    //   104988800  gwb bf16 [8][2][2048][1024] 67108864  -> end ~172 MB
    char* ws = (char*)d_ws;
    int* cursor = (int*)ws;
    int*   tok_slot      = (int*)(ws + 128);
    float* w_slot        = (float*)(ws + 65664);
    unsigned short* xb   = (unsigned short*)(ws + 131200);
    unsigned short* act  = (unsigned short*)(ws + 4325504);
    unsigned short* lwT  = (unsigned short*)(ws + 71434368);
    unsigned short* gwb  = (unsigned short*)(ws + 104988800);

    hipMemsetAsync(d_ws, 0, 128, stream);
    hipMemsetAsync(d_out, 0, (size_t)out_size * sizeof(float), stream);

    router_kernel<<<NTOK / 4, 256, 0, stream>>>(x, rscale, rw, pes, cursor,
                                                tok_slot, w_slot, xb);

    prep_weights<<<GW_BLOCKS + TL_BLOCKS, 256, 0, stream>>>(gw, gwb, lw, lwT);

    dim3 g2(NH / BH, NTOK / BM, NE);   // 32 x 16 x 8, early-exit
    gate_gemm<<<g2, 256, 0, stream>>>(xb, gwb, cursor, tok_slot, w_slot, act);

    dim3 g3(ND / DBN, NTOK / DBM, NE * KSPLIT); // 8 x 16 x 16
    down_gemm<<<g3, 256, 0, stream>>>(act, lwT, cursor, tok_slot, out);
}